// Round 10
// baseline (21.955 us; speedup 1.0000x reference)
//
#include <hip/hip_runtime.h>
#include <math.h>

#define ALPHA 0.2f

// Shapes fixed by harness: B=4, N=512, IN=128, OUT=64.
//
// Algebraic collapse (verified R1-R9):
//  i < 256 : hp_i = (w0*S0 + w1*S1)/(256*(w0+w1)); w0=exp(lrelu(g[2i])),
//            w1=exp(lrelu(g[2i+1])); g = p+q; p=X·wa1, q=X·wa2 (wa=W@a half)
//  i >= 256: all rows identical: R2 = (xt@W)/(2Z);
//            xt = sum_jj ec[jj]*(x_jj+x_{jj+256}); ec=exp(lrelu(p[2jj]+q[2jj+1]))
//  S0/S1 = (colsum of X row-halves)@W. Max-subtraction dropped (verified R5/R7).
//
// v10 = v9 (64 blocks x 256 thr, one spin gate, publish-then-read ws protocol,
// replay-safe flag reset) with a shorter serial chain:
//  - wave 0 alone runs ec->partials->publish->wave-level vmcnt drain->arr flag
//    (removes 2 block barriers); waves 1-3 precompute epilogue softmax weights.
//  - dn flag released right after the gate barrier (only guards arr reset),
//    so block 0's tail wait is ~zero; final done-barrier removed.
//  - float4 partial consumption (16 vec loads vs 48 scalar), s_sleep(1) polls,
//    4-accumulator GEMV.
// 5 __syncthreads total. One dispatch, no coop launch.
//
// ws float layout per batch (stride 8192 floats):
//  [0..16) arr flags (u32)  [16..32) dn flags (u32)  [32..48) Zp
//  [64..2112) xs0p[16][128] [2112..4160) xs1p[16][128] [4160..6208) xtp[16][128]

#define MAGIC_ARR 0x13579BDFu
#define MAGIC_DON 0x2468ACE0u

__device__ __forceinline__ unsigned ld_acq(unsigned* p) {
    return __hip_atomic_load(p, __ATOMIC_ACQUIRE, __HIP_MEMORY_SCOPE_AGENT);
}
__device__ __forceinline__ void st_rel(unsigned* p, unsigned v) {
    __hip_atomic_store(p, v, __ATOMIC_RELEASE, __HIP_MEMORY_SCOPE_AGENT);
}
__device__ __forceinline__ void st_rlx(unsigned* p, unsigned v) {
    __hip_atomic_store(p, v, __ATOMIC_RELAXED, __HIP_MEMORY_SCOPE_AGENT);
}
__device__ __forceinline__ void stf(float* p, float v) {
    __hip_atomic_store(p, v, __ATOMIC_RELAXED, __HIP_MEMORY_SCOPE_AGENT);
}

__device__ __forceinline__ void wait16(unsigned* slots, unsigned magic, int lane) {
    for (;;) {
        unsigned v = (lane < 16) ? ld_acq(&slots[lane]) : magic;
        if (__all(v == magic)) return;
        __builtin_amdgcn_s_sleep(1);
    }
}

__global__ __launch_bounds__(256) void gat_v10(
    const float* __restrict__ X, const float* __restrict__ W,
    const float* __restrict__ a, float* __restrict__ out, float* __restrict__ ws)
{
    __shared__ float XB[32][132];          // block's colsum rows, +4 pad
    __shared__ float wa1[128], wa2[128];
    __shared__ float a_s[128];
    __shared__ float p_s[32], q_s[32];
    __shared__ float ecl[16];
    __shared__ float4 epw[16];             // per-A-row (w0, w1, inv, -)
    __shared__ float xs_l[3][128];         // xs0, xs1, xt (summed)
    __shared__ float Sc[3][64];            // S0, S1, elu(R2)
    __shared__ float zsc;

    const int tid  = threadIdx.x;
    const int wid  = tid >> 6, lane = tid & 63;
    const int b    = blockIdx.x >> 4;
    const int r    = blockIdx.x & 15;
    const float* Xb = X + b * 65536;

    float*    wsF  = ws + b * 8192;
    unsigned* arr  = (unsigned*)wsF;
    unsigned* dn   = (unsigned*)wsF + 16;
    float*    Zp   = wsF + 32;
    float*    xs0p = wsF + 64;

    // ---- issue global loads ----
    const int k2 = tid >> 1, hf = tid & 1;             // wa: W[k2][hf*32..+32)
    const float4* wr = (const float4*)(W + k2 * 64 + hf * 32);
    float4 wv[8];
#pragma unroll
    for (int i = 0; i < 8; ++i) wv[i] = wr[i];

    const int ra = tid >> 3, oct = tid & 7;            // rowsA: [32r+ra][oct*16..)
    const float4* xrA = (const float4*)(Xb + (32 * r + ra) * 128 + oct * 16);
    float4 xa[4];
#pragma unroll
    for (int i = 0; i < 4; ++i) xa[i] = xrA[i];

    const int gi = (ra < 16) ? (16 * r + ra) : (256 + 16 * r + (ra - 16));
    const float4* xrB = (const float4*)(Xb + gi * 128 + oct * 16);
    float4 xb[4];
#pragma unroll
    for (int i = 0; i < 4; ++i) xb[i] = xrB[i];

    if (tid < 128) a_s[tid] = a[tid];
    __syncthreads();                                   // bar1: a_s

    // ---- wa1 = W@a1, wa2 = W@a2 (half-dots over hf) ----
    {
        float r1 = 0.f, r2 = 0.f;
#pragma unroll
        for (int i = 0; i < 8; ++i) {
            const float4 w4 = wv[i];
            const int j = hf * 32 + i * 4;
            r1 = fmaf(w4.x, a_s[j],     r1); r2 = fmaf(w4.x, a_s[64 + j],     r2);
            r1 = fmaf(w4.y, a_s[j + 1], r1); r2 = fmaf(w4.y, a_s[64 + j + 1], r2);
            r1 = fmaf(w4.z, a_s[j + 2], r1); r2 = fmaf(w4.z, a_s[64 + j + 2], r2);
            r1 = fmaf(w4.w, a_s[j + 3], r1); r2 = fmaf(w4.w, a_s[64 + j + 3], r2);
        }
        r1 += __shfl_xor(r1, 1);
        r2 += __shfl_xor(r2, 1);
        if (hf == 0) { wa1[k2] = r1; wa2[k2] = r2; }
    }
    // rowsB -> LDS
#pragma unroll
    for (int i = 0; i < 4; ++i)
        *(float4*)&XB[ra][oct * 16 + i * 4] = xb[i];
    __syncthreads();                                   // bar2: wa + XB

    // ---- p,q dots for rowsA (8 thr/row) ----
    {
        float pp = 0.f, qq = 0.f;
#pragma unroll
        for (int i = 0; i < 4; ++i) {
            const float4 x4 = xa[i];
            const int j = oct * 16 + i * 4;
            pp = fmaf(x4.x, wa1[j],     pp); qq = fmaf(x4.x, wa2[j],     qq);
            pp = fmaf(x4.y, wa1[j + 1], pp); qq = fmaf(x4.y, wa2[j + 1], qq);
            pp = fmaf(x4.z, wa1[j + 2], pp); qq = fmaf(x4.z, wa2[j + 2], qq);
            pp = fmaf(x4.w, wa1[j + 3], pp); qq = fmaf(x4.w, wa2[j + 3], qq);
        }
        pp += __shfl_xor(pp, 1); qq += __shfl_xor(qq, 1);
        pp += __shfl_xor(pp, 2); qq += __shfl_xor(qq, 2);
        pp += __shfl_xor(pp, 4); qq += __shfl_xor(qq, 4);
        if (oct == 0) { p_s[ra] = pp; q_s[ra] = qq; }
    }
    __syncthreads();                                   // bar3: p_s,q_s

    // ---- wave 0: ec -> partials -> publish -> flag;  wave 1: epw precompute --
    if (wid == 0) {
        // ec (block-local rows): lanes 0..15 write ecl, same wave reads below
        float ecv = 0.f;
        if (lane < 16) {
            float cc = p_s[2 * lane] + q_s[2 * lane + 1];
            cc = cc > 0.f ? cc : ALPHA * cc;
            ecv = __expf(cc);
            ecl[lane] = ecv;
        }
        float z = ecv;
        z += __shfl_xor(z, 1); z += __shfl_xor(z, 2);
        z += __shfl_xor(z, 4); z += __shfl_xor(z, 8);
        if (lane == 0) stf(&Zp[r], z);

        // partials for k = lane and k = lane+64 (XB column reads: 2-way, free)
        float s0a = 0.f, s1a = 0.f, sta = 0.f;
        float s0b = 0.f, s1b = 0.f, stb = 0.f;
#pragma unroll
        for (int i = 0; i < 16; ++i) {
            const float e  = ecl[i];
            const float va = XB[i][lane],      vb = XB[16 + i][lane];
            const float wa = XB[i][lane + 64], wb = XB[16 + i][lane + 64];
            s0a += va; s1a += vb; sta = fmaf(e, va + vb, sta);
            s0b += wa; s1b += wb; stb = fmaf(e, wa + wb, stb);
        }
        stf(&xs0p[r * 128 + lane],             s0a);
        stf(&xs0p[r * 128 + lane + 64],        s0b);
        stf(&xs0p[2048 + r * 128 + lane],      s1a);
        stf(&xs0p[2048 + r * 128 + lane + 64], s1b);
        stf(&xs0p[4096 + r * 128 + lane],      sta);
        stf(&xs0p[4096 + r * 128 + lane + 64], stb);
        // wave-level drain: vmcnt counts ALL 64 lanes' stores of this wave
        asm volatile("s_waitcnt vmcnt(0)" ::: "memory");
        __builtin_amdgcn_sched_barrier(0);
        if (lane == 0) st_rel(&arr[r], MAGIC_ARR);
    } else if (tid >= 64 && tid < 80) {
        // epilogue softmax weights for this block's 16 A-rows
        const int li = tid - 64;
        float u = p_s[2 * li]     + q_s[2 * li];
        float v = p_s[2 * li + 1] + q_s[2 * li + 1];
        u = u > 0.f ? u : ALPHA * u;
        v = v > 0.f ? v : ALPHA * v;
        const float w0 = __expf(u), w1 = __expf(v);
        float4 e;
        e.x = w0; e.y = w1; e.z = 1.f / (256.f * (w0 + w1)); e.w = 0.f;
        epw[li] = e;
    }

    // ---- the one inter-block gate ----
    wait16(arr, MAGIC_ARR, lane);

    // ---- consume partials (float4, fixed order; plain loads ok post-acquire) --
    if (tid < 96) {
        const int g = tid >> 5, k4 = tid & 31;
        const float4* src = (const float4*)(xs0p + g * 2048) + k4;
        float4 s; s.x = 0.f; s.y = 0.f; s.z = 0.f; s.w = 0.f;
#pragma unroll
        for (int j = 0; j < 16; ++j) {
            const float4 v = src[j * 32];
            s.x += v.x; s.y += v.y; s.z += v.z; s.w += v.w;
        }
        *(float4*)&xs_l[g][4 * k4] = s;
    } else if (tid == 96) {
        float z = 0.f;
#pragma unroll
        for (int j = 0; j < 16; ++j) z += Zp[j];
        zsc = z;
    }
    __syncthreads();                                   // bar4: xs_l/zsc + all waves past gate

    if (tid == 0) st_rel(&dn[r], MAGIC_DON);           // safe: block no longer spins

    // ---- GEMVs through W: S0, S1, R2 (pre-ELU) ----
    if (tid < 192) {
        const int g = wid;
        float a0 = 0.f, a1 = 0.f, a2 = 0.f, a3 = 0.f;
#pragma unroll
        for (int k = 0; k < 128; k += 4) {
            a0 = fmaf(xs_l[g][k],     W[(k)     * 64 + lane], a0);
            a1 = fmaf(xs_l[g][k + 1], W[(k + 1) * 64 + lane], a1);
            a2 = fmaf(xs_l[g][k + 2], W[(k + 2) * 64 + lane], a2);
            a3 = fmaf(xs_l[g][k + 3], W[(k + 3) * 64 + lane], a3);
        }
        float acc = (a0 + a1) + (a2 + a3);
        if (g == 2) {
            acc /= (2.f * zsc);
            acc = acc > 0.f ? acc : expm1f(acc);
        }
        Sc[g][lane] = acc;
    }
    __syncthreads();                                   // bar5: Sc

    // ---- epilogue: A-rows [16r,+16), B-rows [256+16r,+16) ----
    {
        const int li = tid >> 4, c4 = (tid & 15) << 2;
        const float4 e  = epw[li];
        const float4 s0 = *(const float4*)&Sc[0][c4];
        const float4 s1 = *(const float4*)&Sc[1][c4];
        float4 o;
        o.x = (e.x * s0.x + e.y * s1.x) * e.z;
        o.y = (e.x * s0.y + e.y * s1.y) * e.z;
        o.z = (e.x * s0.z + e.y * s1.z) * e.z;
        o.w = (e.x * s0.w + e.y * s1.w) * e.z;
        o.x = o.x > 0.f ? o.x : expm1f(o.x);
        o.y = o.y > 0.f ? o.y : expm1f(o.y);
        o.z = o.z > 0.f ? o.z : expm1f(o.z);
        o.w = o.w > 0.f ? o.w : expm1f(o.w);
        *(float4*)(out + (b * 512 + 16 * r + li) * 64 + c4) = o;
        *(float4*)(out + (b * 512 + 256 + 16 * r + li) * 64 + c4) =
            *(const float4*)&Sc[2][c4];
    }

    // ---- tail: block 0 of each batch resets flags (dn set ~1us ago -> ~no wait)
    if (r == 0 && wid == 0) {
        wait16(dn, MAGIC_DON, lane);
        if (lane < 16) { st_rlx(&arr[lane], 0u); st_rlx(&dn[lane], 0u); }
    }
}

extern "C" void kernel_launch(void* const* d_in, const int* in_sizes, int n_in,
                              void* d_out, int out_size, void* d_ws, size_t ws_size,
                              hipStream_t stream) {
    const float* X = (const float*)d_in[0];   // (4,512,128)
    // d_in[1] = adj — dead code in the reference
    const float* W = (const float*)d_in[2];   // (128,64)
    const float* a = (const float*)d_in[3];   // (128,1)
    float* out = (float*)d_out;               // (4,512,64)

    hipLaunchKernelGGL(gat_v10, dim3(64), dim3(256), 0, stream,
                       X, W, a, out, (float*)d_ws);
}

// Round 11
// 18.123 us; speedup vs baseline: 1.2114x; 1.2114x over previous
//
#include <hip/hip_runtime.h>
#include <math.h>

#define ALPHA 0.2f

// Shapes fixed by harness: B=4, N=512, IN=128, OUT=64.
//
// Algebraic collapse (verified R1-R10):
//  i < 256 : hp_i = (w0*S0 + w1*S1)/(256*(w0+w1)); w0=exp(lrelu(g[2i])),
//            w1=exp(lrelu(g[2i+1])); g = p+q; p=X·wa1, q=X·wa2 (wa=W@a half)
//  i >= 256: all rows identical: R2 = (xt@W)/(2Z);
//            xt = sum_jj ec[jj]*(x_jj+x_{jj+256}); ec=exp(lrelu(p[2jj]+q[2jj+1]))
//  S0/S1 = (colsum of X row-halves)@W. Max-subtraction dropped (verified R5/R7).
//
// v11 = v9 skeleton (64 blocks x 256 thr; block-wide 128-thread partial
// publish -> ONE inter-block gate; publish-then-read ws protocol, replay-safe
// flag reset; R10 lesson: keep the flag-release path WIDE) + benign trims:
//  - float4 partial consumption (16 vec loads vs 48 scalar)
//  - s_sleep(1) polls
//  - dn released after consume-barrier (drops the post-epilogue barrier)
//  - 4-accumulator GEMV
//
// ws float layout per batch (stride 8192 floats):
//  [0..16) arr flags (u32)  [16..32) dn flags (u32)  [32..48) Zp
//  [64..2112) xs0p[16][128] [2112..4160) xs1p[16][128] [4160..6208) xtp[16][128]

#define MAGIC_ARR 0x13579BDFu
#define MAGIC_DON 0x2468ACE0u

__device__ __forceinline__ unsigned ld_acq(unsigned* p) {
    return __hip_atomic_load(p, __ATOMIC_ACQUIRE, __HIP_MEMORY_SCOPE_AGENT);
}
__device__ __forceinline__ void st_rel(unsigned* p, unsigned v) {
    __hip_atomic_store(p, v, __ATOMIC_RELEASE, __HIP_MEMORY_SCOPE_AGENT);
}
__device__ __forceinline__ void st_rlx(unsigned* p, unsigned v) {
    __hip_atomic_store(p, v, __ATOMIC_RELAXED, __HIP_MEMORY_SCOPE_AGENT);
}
__device__ __forceinline__ float ldf(float* p) {
    return __hip_atomic_load(p, __ATOMIC_RELAXED, __HIP_MEMORY_SCOPE_AGENT);
}
__device__ __forceinline__ void stf(float* p, float v) {
    __hip_atomic_store(p, v, __ATOMIC_RELAXED, __HIP_MEMORY_SCOPE_AGENT);
}

__device__ __forceinline__ void wait16(unsigned* slots, unsigned magic, int lane) {
    for (;;) {
        unsigned v = (lane < 16) ? ld_acq(&slots[lane]) : magic;
        if (__all(v == magic)) return;
        __builtin_amdgcn_s_sleep(1);
    }
}

__global__ __launch_bounds__(256) void gat_v11(
    const float* __restrict__ X, const float* __restrict__ W,
    const float* __restrict__ a, float* __restrict__ out, float* __restrict__ ws)
{
    __shared__ float XB[32][132];          // block's colsum rows, +4 pad
    __shared__ float wa1[128], wa2[128];
    __shared__ float a_s[128];
    __shared__ float p_s[32], q_s[32];
    __shared__ float ecl[16];
    __shared__ float xs_l[3][128];         // xs0, xs1, xt (summed)
    __shared__ float Sc[3][64];            // S0, S1, elu(R2)
    __shared__ float zsc;

    const int tid  = threadIdx.x;
    const int lane = tid & 63;
    const int b    = blockIdx.x >> 4;
    const int r    = blockIdx.x & 15;
    const float* Xb = X + b * 65536;

    float*    wsF  = ws + b * 8192;
    unsigned* arr  = (unsigned*)wsF;
    unsigned* dn   = (unsigned*)wsF + 16;
    float*    Zp   = wsF + 32;
    float*    xs0p = wsF + 64;

    // ---- issue global loads ----
    const int k2 = tid >> 1, hf = tid & 1;             // wa: W[k2][hf*32..+32)
    const float4* wr = (const float4*)(W + k2 * 64 + hf * 32);
    float4 wv[8];
#pragma unroll
    for (int i = 0; i < 8; ++i) wv[i] = wr[i];

    const int ra = tid >> 3, oct = tid & 7;            // rowsA: [32r+ra][oct*16..)
    const float4* xrA = (const float4*)(Xb + (32 * r + ra) * 128 + oct * 16);
    float4 xa[4];
#pragma unroll
    for (int i = 0; i < 4; ++i) xa[i] = xrA[i];

    const int gi = (ra < 16) ? (16 * r + ra) : (256 + 16 * r + (ra - 16));
    const float4* xrB = (const float4*)(Xb + gi * 128 + oct * 16);
    float4 xb[4];
#pragma unroll
    for (int i = 0; i < 4; ++i) xb[i] = xrB[i];

    if (tid < 128) a_s[tid] = a[tid];
    __syncthreads();                                   // bar1: a_s

    // ---- wa1 = W@a1, wa2 = W@a2 (half-dots over hf) ----
    {
        float r1 = 0.f, r2 = 0.f;
#pragma unroll
        for (int i = 0; i < 8; ++i) {
            const float4 w4 = wv[i];
            const int j = hf * 32 + i * 4;
            r1 = fmaf(w4.x, a_s[j],     r1); r2 = fmaf(w4.x, a_s[64 + j],     r2);
            r1 = fmaf(w4.y, a_s[j + 1], r1); r2 = fmaf(w4.y, a_s[64 + j + 1], r2);
            r1 = fmaf(w4.z, a_s[j + 2], r1); r2 = fmaf(w4.z, a_s[64 + j + 2], r2);
            r1 = fmaf(w4.w, a_s[j + 3], r1); r2 = fmaf(w4.w, a_s[64 + j + 3], r2);
        }
        r1 += __shfl_xor(r1, 1);
        r2 += __shfl_xor(r2, 1);
        if (hf == 0) { wa1[k2] = r1; wa2[k2] = r2; }
    }
    // rowsB -> LDS
#pragma unroll
    for (int i = 0; i < 4; ++i)
        *(float4*)&XB[ra][oct * 16 + i * 4] = xb[i];
    __syncthreads();                                   // bar2: wa + XB

    // ---- p,q dots for rowsA (8 thr/row) ----
    {
        float pp = 0.f, qq = 0.f;
#pragma unroll
        for (int i = 0; i < 4; ++i) {
            const float4 x4 = xa[i];
            const int j = oct * 16 + i * 4;
            pp = fmaf(x4.x, wa1[j],     pp); qq = fmaf(x4.x, wa2[j],     qq);
            pp = fmaf(x4.y, wa1[j + 1], pp); qq = fmaf(x4.y, wa2[j + 1], qq);
            pp = fmaf(x4.z, wa1[j + 2], pp); qq = fmaf(x4.z, wa2[j + 2], qq);
            pp = fmaf(x4.w, wa1[j + 3], pp); qq = fmaf(x4.w, wa2[j + 3], qq);
        }
        pp += __shfl_xor(pp, 1); qq += __shfl_xor(qq, 1);
        pp += __shfl_xor(pp, 2); qq += __shfl_xor(qq, 2);
        pp += __shfl_xor(pp, 4); qq += __shfl_xor(qq, 4);
        if (oct == 0) { p_s[ra] = pp; q_s[ra] = qq; }
    }
    __syncthreads();                                   // bar3: p_s,q_s

    // ---- ec (block-local!) + Zp publish ----
    if (tid < 16) {
        float cc = p_s[2 * tid] + q_s[2 * tid + 1];
        cc = cc > 0.f ? cc : ALPHA * cc;
        const float ecv = __expf(cc);
        ecl[tid] = ecv;
        float z = ecv;
        z += __shfl_xor(z, 1); z += __shfl_xor(z, 2);
        z += __shfl_xor(z, 4); z += __shfl_xor(z, 8);
        if (tid == 0) stf(&Zp[r], z);
    }
    __syncthreads();                                   // bar4: ecl

    // ---- partials: xs0, xs1, xt -> publish (block-wide, 128 threads) ----
    if (tid < 128) {
        const int k = tid;
        float s0 = 0.f, s1 = 0.f, st = 0.f;
#pragma unroll
        for (int i = 0; i < 16; ++i) {
            const float va = XB[i][k];
            const float vb = XB[16 + i][k];
            s0 += va; s1 += vb;
            st = fmaf(ecl[i], va + vb, st);
        }
        stf(&xs0p[r * 128 + k], s0);
        stf(&xs0p[2048 + r * 128 + k], s1);
        stf(&xs0p[4096 + r * 128 + k], st);
    }
    __syncthreads();                                   // bar5: drains publishes (vmcnt0)
    if (tid == 0) st_rel(&arr[r], MAGIC_ARR);

    // ---- the one inter-block gate ----
    wait16(arr, MAGIC_ARR, lane);

    // ---- consume partials (float4, fixed order; plain loads ok post-acquire) --
    if (tid < 96) {
        const int g = tid >> 5, k4 = tid & 31;
        const float4* src = (const float4*)(xs0p + g * 2048) + k4;
        float4 s; s.x = 0.f; s.y = 0.f; s.z = 0.f; s.w = 0.f;
#pragma unroll
        for (int j = 0; j < 16; ++j) {
            const float4 v = src[j * 32];
            s.x += v.x; s.y += v.y; s.z += v.z; s.w += v.w;
        }
        *(float4*)&xs_l[g][4 * k4] = s;
    } else if (tid == 96) {
        float z = 0.f;
#pragma unroll
        for (int j = 0; j < 16; ++j) z += ldf(&Zp[j]);
        zsc = z;
    }
    __syncthreads();                                   // bar6: xs_l/zsc; all waves past gate

    if (tid == 0) st_rel(&dn[r], MAGIC_DON);           // safe: block no longer spins on arr

    // ---- GEMVs through W: S0, S1, R2 (pre-ELU) ----
    if (tid < 192) {
        const int g = tid >> 6;
        float a0 = 0.f, a1 = 0.f, a2 = 0.f, a3 = 0.f;
#pragma unroll
        for (int k = 0; k < 128; k += 4) {
            a0 = fmaf(xs_l[g][k],     W[(k)     * 64 + lane], a0);
            a1 = fmaf(xs_l[g][k + 1], W[(k + 1) * 64 + lane], a1);
            a2 = fmaf(xs_l[g][k + 2], W[(k + 2) * 64 + lane], a2);
            a3 = fmaf(xs_l[g][k + 3], W[(k + 3) * 64 + lane], a3);
        }
        float acc = (a0 + a1) + (a2 + a3);
        if (g == 2) {
            acc /= (2.f * zsc);
            acc = acc > 0.f ? acc : expm1f(acc);
        }
        Sc[g][lane] = acc;
    }
    __syncthreads();                                   // bar7: Sc

    // ---- epilogue: A-rows [16r,+16), B-rows [256+16r,+16) ----
    {
        const int li = tid >> 4, c4 = (tid & 15) << 2;
        float u = p_s[2 * li]     + q_s[2 * li];
        float v = p_s[2 * li + 1] + q_s[2 * li + 1];
        u = u > 0.f ? u : ALPHA * u;
        v = v > 0.f ? v : ALPHA * v;
        const float w0 = __expf(u), w1 = __expf(v);
        const float inv = 1.f / (256.f * (w0 + w1));
        const float4 s0 = *(const float4*)&Sc[0][c4];
        const float4 s1 = *(const float4*)&Sc[1][c4];
        float4 o;
        o.x = (w0 * s0.x + w1 * s1.x) * inv;
        o.y = (w0 * s0.y + w1 * s1.y) * inv;
        o.z = (w0 * s0.z + w1 * s1.z) * inv;
        o.w = (w0 * s0.w + w1 * s1.w) * inv;
        o.x = o.x > 0.f ? o.x : expm1f(o.x);
        o.y = o.y > 0.f ? o.y : expm1f(o.y);
        o.z = o.z > 0.f ? o.z : expm1f(o.z);
        o.w = o.w > 0.f ? o.w : expm1f(o.w);
        *(float4*)(out + (b * 512 + 16 * r + li) * 64 + c4) = o;
        *(float4*)(out + (b * 512 + 256 + 16 * r + li) * 64 + c4) =
            *(const float4*)&Sc[2][c4];
    }

    // ---- tail: block 0 of each batch resets flags (dn long set -> ~no wait) ----
    if (r == 0 && tid < 64) {
        wait16(dn, MAGIC_DON, lane);
        if (lane < 16) { st_rlx(&arr[lane], 0u); st_rlx(&dn[lane], 0u); }
    }
}

extern "C" void kernel_launch(void* const* d_in, const int* in_sizes, int n_in,
                              void* d_out, int out_size, void* d_ws, size_t ws_size,
                              hipStream_t stream) {
    const float* X = (const float*)d_in[0];   // (4,512,128)
    // d_in[1] = adj — dead code in the reference
    const float* W = (const float*)d_in[2];   // (128,64)
    const float* a = (const float*)d_in[3];   // (128,1)
    float* out = (float*)d_out;               // (4,512,64)

    hipLaunchKernelGGL(gat_v11, dim3(64), dim3(256), 0, stream,
                       X, W, a, out, (float*)d_ws);
}